// Round 9
// baseline (42.634 us; speedup 1.0000x reference)
//
#include <hip/hip_runtime.h>

typedef float floatx2 __attribute__((ext_vector_type(2)));
typedef float floatx4 __attribute__((ext_vector_type(4)));

constexpr int BLOCK = 256;   // 4 waves
constexpr int MPW   = 4;     // models per wave (E in VGPRs, no LDS)
constexpr int SUB   = 4;     // 256-point subtiles per wave
constexpr int TILE_PTS = 64 * 4 * SUB;        // 1024 points per block/wave sweep
constexpr int MPB   = 4 * MPW;                // 16 models per block

static __device__ __forceinline__ floatx2 fma2(floatx2 a, floatx2 b, floatx2 c) {
    return __builtin_elementwise_fma(a, b, c);   // -> v_pk_fma_f32 (verified round 7)
}

__global__ __launch_bounds__(BLOCK) void essential_msac_kernel(
    const float*  __restrict__ models,  // B x 3 x 4
    const float4* __restrict__ pts,     // N x (x1,y1,x2,y2)
    const float*  __restrict__ K1,      // 3x3
    const float*  __restrict__ K2,      // 3x3
    float*        __restrict__ out,     // B x N
    int B, int N)
{
    const int wq   = threadIdx.x >> 6;          // wave id 0..3
    const int lane = threadIdx.x & 63;
    const int bm   = blockIdx.y * MPB + wq * MPW;   // this wave's first model

    // ---- Build 4 E matrices in registers (wave-uniform global loads, once) ----
    const float* mm = models + (size_t)bm * 12;
    float E[MPW][9];
    #pragma unroll
    for (int mi = 0; mi < MPW; ++mi) {
        const float* m = mm + mi * 12;
        const float t0 = m[3], t1 = m[7], t2 = m[11];
        #pragma unroll
        for (int j = 0; j < 3; ++j) {
            const float R0 = m[0 + j], R1 = m[4 + j], R2 = m[8 + j];
            E[mi][0 + j] = fmaf(-t2, R1,  t1 * R2);
            E[mi][3 + j] = fmaf( t2, R0, -t0 * R2);
            E[mi][6 + j] = fmaf(-t1, R0,  t0 * R1);
        }
    }

    const float f1 = (K1[0] + K1[4]) * 0.5f;
    const float f2 = (K2[0] + K2[4]) * 0.5f;
    const float thr  = (1.0f / f1 + 1.0f / f2) * 0.5f;
    const float thr2 = thr * thr;
    const floatx2 thr2v = { thr2,  thr2 };
    const floatx2 onev  = { 1.0f,  1.0f };
    const floatx2 nonev = { -1.0f, -1.0f };
    const floatx2 zerov = { 0.0f,  0.0f };

    // ---- Load 4 subtiles x 4 points, packed as point-pairs ----
    const int nb = blockIdx.x * TILE_PTS + lane * 4;   // subtile-0 base for this lane
    floatx2 px[SUB][2], py[SUB][2], pu[SUB][2], pv[SUB][2];
    #pragma unroll
    for (int s = 0; s < SUB; ++s) {
        const int n0s = nb + s * 256;
        float4 p[4];
        #pragma unroll
        for (int k = 0; k < 4; ++k) {
            const int idx = min(n0s + k, N - 1);    // clamp; masked on store
            p[k] = pts[idx];
        }
        #pragma unroll
        for (int g = 0; g < 2; ++g) {
            px[s][g] = { p[2*g].x, p[2*g+1].x };
            py[s][g] = { p[2*g].y, p[2*g+1].y };
            pu[s][g] = { p[2*g].z, p[2*g+1].z };
            pv[s][g] = { p[2*g].w, p[2*g+1].w };
        }
    }

    // ---- 4 models x 4 subtiles: pure packed VALU + coalesced stores ----
    #pragma unroll
    for (int mi = 0; mi < MPW; ++mi) {
        const float* e = E[mi];
        const floatx2 E0 = {e[0],e[0]}, E1 = {e[1],e[1]}, E2 = {e[2],e[2]};
        const floatx2 E3 = {e[3],e[3]}, E4 = {e[4],e[4]}, E5 = {e[5],e[5]};
        const floatx2 E6 = {e[6],e[6]}, E7 = {e[7],e[7]}, E8 = {e[8],e[8]};
        float* orow = out + (size_t)(bm + mi) * N;

        #pragma unroll
        for (int s = 0; s < SUB; ++s) {
            floatx2 rr[2];
            #pragma unroll
            for (int g = 0; g < 2; ++g) {
                const floatx2 a0 = fma2(E0, px[s][g], fma2(E1, py[s][g], E2));
                const floatx2 a1 = fma2(E3, px[s][g], fma2(E4, py[s][g], E5));
                const floatx2 b0 = fma2(E0, pu[s][g], fma2(E3, pv[s][g], E6));
                const floatx2 b1 = fma2(E1, pu[s][g], fma2(E4, pv[s][g], E7));
                const floatx2 b2 = fma2(E2, pu[s][g], fma2(E5, pv[s][g], E8));

                const floatx2 jj  = fma2(a0, a0, fma2(a1, a1, fma2(b0, b0, b1 * b1)));
                const floatx2 sv  = fma2(px[s][g], b0, fma2(py[s][g], b1, b2));
                const floatx2 num = sv * sv;
                const floatx2 jjt = jj * thr2v;
                const floatx2 rj  = { __builtin_amdgcn_rcpf(jjt.x),
                                      __builtin_amdgcn_rcpf(jjt.y) };
                const floatx2 d   = num * rj;
                const floatx2 r   = fma2(d, nonev, onev);     // 1 - d
                rr[g] = __builtin_elementwise_max(r, zerov);
            }

            const int n0s = nb + s * 256;
            if (n0s + 4 <= N) {
                floatx4 v4 = { rr[0].x, rr[0].y, rr[1].x, rr[1].y };
                *reinterpret_cast<floatx4*>(orow + n0s) = v4;
            } else {
                const float rs[4] = { rr[0].x, rr[0].y, rr[1].x, rr[1].y };
                for (int k = 0; k < 4 && n0s + k < N; ++k) orow[n0s + k] = rs[k];
            }
        }
    }
}

extern "C" void kernel_launch(void* const* d_in, const int* in_sizes, int n_in,
                              void* d_out, int out_size, void* d_ws, size_t ws_size,
                              hipStream_t stream)
{
    const float* models = (const float*)d_in[0];
    const float* points = (const float*)d_in[1];
    const float* K1     = (const float*)d_in[2];
    const float* K2     = (const float*)d_in[3];
    float* out = (float*)d_out;

    const int B = in_sizes[0] / 12;   // (B,3,4) = 512
    const int N = in_sizes[1] / 4;    // (N,4)   = 100000

    dim3 grid((N + TILE_PTS - 1) / TILE_PTS,   // 98
              (B + MPB - 1) / MPB);            // 32
    essential_msac_kernel<<<grid, BLOCK, 0, stream>>>(
        models, (const float4*)points, K1, K2, out, B, N);
}